// Round 2
// baseline (556.967 us; speedup 1.0000x reference)
//
#include <hip/hip_runtime.h>
#include <hip/hip_bf16.h>

#define BB   2048
#define SS   256
#define NTOK (BB*SS)
#define FIN  3
#define CND  4
#define EMB  4
#define HID  64
#define NC   256
#define TPB  128

// f32 weights copied to fixed __device__ globals (wave-uniform addresses ->
// compiler emits s_load + v_fmac v,s,v; zero VMEM cost per FMA in the hot loop).
__device__ float g_ew1[(FIN+CND)*HID];
__device__ float g_eb1[HID];
__device__ float g_ew2[HID*HID];
__device__ float g_eb2[HID];
__device__ float g_ew3[HID*EMB];
__device__ float g_eb3[EMB];
__device__ float g_cb [NC*EMB];
__device__ float g_cc [NC];
__device__ float g_dw1[(EMB+CND)*HID];
__device__ float g_db1[HID];
__device__ float g_dw2[HID*HID];
__device__ float g_db2[HID];
__device__ float g_dw3[HID*FIN];
__device__ float g_db3[FIN];
__device__ float g_loss;

__global__ void prep_kernel(const float* ew1, const float* eb1, const float* ew2, const float* eb2,
                            const float* ew3, const float* eb3, const float* cb,
                            const float* dw1, const float* db1, const float* dw2, const float* db2,
                            const float* dw3, const float* db3) {
    int t = threadIdx.x;
    for (int i = t; i < (FIN+CND)*HID; i += 256) g_ew1[i] = ew1[i];
    for (int i = t; i < HID;           i += 256) g_eb1[i] = eb1[i];
    for (int i = t; i < HID*HID;       i += 256) g_ew2[i] = ew2[i];
    for (int i = t; i < HID;           i += 256) g_eb2[i] = eb2[i];
    for (int i = t; i < HID*EMB;       i += 256) g_ew3[i] = ew3[i];
    for (int i = t; i < EMB;           i += 256) g_eb3[i] = eb3[i];
    for (int i = t; i < (EMB+CND)*HID; i += 256) g_dw1[i] = dw1[i];
    for (int i = t; i < HID;           i += 256) g_db1[i] = db1[i];
    for (int i = t; i < HID*HID;       i += 256) g_dw2[i] = dw2[i];
    for (int i = t; i < HID;           i += 256) g_db2[i] = db2[i];
    for (int i = t; i < HID*FIN;       i += 256) g_dw3[i] = dw3[i];
    for (int i = t; i < FIN;           i += 256) g_db3[i] = db3[i];
    for (int i = t; i < NC; i += 256) {
        float c0 = cb[i*EMB+0];
        float c1 = cb[i*EMB+1];
        float c2 = cb[i*EMB+2];
        float c3 = cb[i*EMB+3];
        g_cb[i*EMB+0] = c0; g_cb[i*EMB+1] = c1;
        g_cb[i*EMB+2] = c2; g_cb[i*EMB+3] = c3;
        g_cc[i] = ((c0*c0 + c1*c1) + c2*c2) + c3*c3;  // sequential order = np small-n sum
    }
    if (t == 0) g_loss = 0.0f;
}

__global__ __launch_bounds__(TPB) void vqvae_main(const float* __restrict__ x,
                                                  const float* __restrict__ mask,
                                                  const float* __restrict__ cond,
                                                  float* __restrict__ out) {
    __shared__ float sh[HID * TPB];    // per-thread private h[64], stride-TPB across j
    const int tid = threadIdx.x;
    const int n   = blockIdx.x * TPB + tid;
    const int bu  = (blockIdx.x * TPB) >> 8;   // batch index; uniform since TPB divides SS

    const float m = mask[n];

    float cnd[CND];
    #pragma unroll
    for (int i = 0; i < CND; i++) cnd[i] = cond[bu*CND + i];

    float xin[FIN + CND];
    #pragma unroll
    for (int i = 0; i < FIN; i++) xin[i] = x[n*FIN + i] * m;
    #pragma unroll
    for (int i = 0; i < CND; i++) xin[FIN + i] = cnd[i] * m;

    float* hp = &sh[tid];

    // ---- encoder layer 1: 7 -> 64, relu ----
    #pragma unroll
    for (int j = 0; j < HID; j++) {
        float a = xin[0] * g_ew1[j];
        #pragma unroll
        for (int i = 1; i < FIN+CND; i++) a = fmaf(xin[i], g_ew1[i*HID + j], a);
        a += g_eb1[j];
        hp[j*TPB] = fmaxf(a, 0.0f);
    }

    // ---- encoder layer 2: 64 -> 64, relu ----
    float acc[HID];
    #pragma unroll
    for (int j = 0; j < HID; j++) acc[j] = 0.0f;
    #pragma unroll 2
    for (int k = 0; k < HID; k++) {
        float hk = hp[k*TPB];
        #pragma unroll
        for (int j = 0; j < HID; j++) acc[j] = fmaf(hk, g_ew2[k*HID + j], acc[j]);
    }
    #pragma unroll
    for (int j = 0; j < HID; j++) hp[j*TPB] = fmaxf(acc[j] + g_eb2[j], 0.0f);

    // ---- encoder layer 3: 64 -> 4 ----
    float z0 = 0.f, z1 = 0.f, z2 = 0.f, z3 = 0.f;
    #pragma unroll 4
    for (int k = 0; k < HID; k++) {
        float hk = hp[k*TPB];
        z0 = fmaf(hk, g_ew3[k*EMB + 0], z0);
        z1 = fmaf(hk, g_ew3[k*EMB + 1], z1);
        z2 = fmaf(hk, g_ew3[k*EMB + 2], z2);
        z3 = fmaf(hk, g_ew3[k*EMB + 3], z3);
    }
    z0 += g_eb3[0]; z1 += g_eb3[1]; z2 += g_eb3[2]; z3 += g_eb3[3];

    // ---- VQ: argmin over 256 codes of (zz - 2*dot) + cc ----
    const float zz = ((z0*z0 + z1*z1) + z2*z2) + z3*z3;
    float best = 3.4e38f;
    int   bi   = 0;
    #pragma unroll 4
    for (int ci = 0; ci < NC; ci++) {
        float dot = z0 * g_cb[ci*EMB + 0];
        dot = fmaf(z1, g_cb[ci*EMB + 1], dot);
        dot = fmaf(z2, g_cb[ci*EMB + 2], dot);
        dot = fmaf(z3, g_cb[ci*EMB + 3], dot);
        float d = (zz - 2.0f*dot) + g_cc[ci];
        if (d < best) { best = d; bi = ci; }   // strict < : first-min wins (np.argmin)
    }

    // gather chosen code (divergent index -> per-lane vector load)
    float q0 = g_cb[bi*EMB + 0];
    float q1 = g_cb[bi*EMB + 1];
    float q2 = g_cb[bi*EMB + 2];
    float q3 = g_cb[bi*EMB + 3];

    // ---- vq loss partial: (1+beta)/N applied at finalize ----
    float e0 = z0-q0, e1 = z1-q1, e2 = z2-q2, e3 = z3-q3;
    float sq = ((e0*e0 + e1*e1) + e2*e2) + e3*e3;
    #pragma unroll
    for (int off = 32; off > 0; off >>= 1) sq += __shfl_down(sq, off, 64);
    if ((tid & 63) == 0) atomicAdd(&g_loss, sq);

    // ---- decoder ----
    float zd[EMB + CND];
    zd[0] = q0*m; zd[1] = q1*m; zd[2] = q2*m; zd[3] = q3*m;
    #pragma unroll
    for (int i = 0; i < CND; i++) zd[EMB + i] = cnd[i] * m;

    #pragma unroll
    for (int j = 0; j < HID; j++) {
        float a = zd[0] * g_dw1[j];
        #pragma unroll
        for (int i = 1; i < EMB+CND; i++) a = fmaf(zd[i], g_dw1[i*HID + j], a);
        a += g_db1[j];
        hp[j*TPB] = fmaxf(a, 0.0f);
    }

    #pragma unroll
    for (int j = 0; j < HID; j++) acc[j] = 0.0f;
    #pragma unroll 2
    for (int k = 0; k < HID; k++) {
        float hk = hp[k*TPB];
        #pragma unroll
        for (int j = 0; j < HID; j++) acc[j] = fmaf(hk, g_dw2[k*HID + j], acc[j]);
    }
    #pragma unroll
    for (int j = 0; j < HID; j++) hp[j*TPB] = fmaxf(acc[j] + g_db2[j], 0.0f);

    float r0 = 0.f, r1 = 0.f, r2 = 0.f;
    #pragma unroll 4
    for (int k = 0; k < HID; k++) {
        float hk = hp[k*TPB];
        r0 = fmaf(hk, g_dw3[k*FIN + 0], r0);
        r1 = fmaf(hk, g_dw3[k*FIN + 1], r1);
        r2 = fmaf(hk, g_dw3[k*FIN + 2], r2);
    }
    r0 += g_db3[0]; r1 += g_db3[1]; r2 += g_db3[2];

    // ---- outputs: [x_reco (f32) | vq_loss (f32) | idx (as f32 value)] ----
    out[n*FIN + 0] = r0;
    out[n*FIN + 1] = r1;
    out[n*FIN + 2] = r2;
    out[NTOK*FIN + 1 + n] = (float)bi;
}

__global__ void finalize_kernel(float* out) {
    // loss = mean((z-zq)^2) + 0.25*mean((z-zq)^2) = 1.25 * sum / (N*EMB)
    out[NTOK*FIN] = 1.25f * g_loss * (1.0f / (float)(NTOK*EMB));
}

extern "C" void kernel_launch(void* const* d_in, const int* in_sizes, int n_in,
                              void* d_out, int out_size, void* d_ws, size_t ws_size,
                              hipStream_t stream) {
    (void)in_sizes; (void)n_in; (void)d_ws; (void)ws_size; (void)out_size;
    const float* x    = (const float*)d_in[0];
    const float* mask = (const float*)d_in[1];
    const float* cond = (const float*)d_in[2];

    prep_kernel<<<1, 256, 0, stream>>>(
        (const float*)d_in[3],  (const float*)d_in[4],  (const float*)d_in[5],
        (const float*)d_in[6],  (const float*)d_in[7],  (const float*)d_in[8],
        (const float*)d_in[9],  (const float*)d_in[10], (const float*)d_in[11],
        (const float*)d_in[12], (const float*)d_in[13], (const float*)d_in[14],
        (const float*)d_in[15]);

    vqvae_main<<<NTOK/TPB, TPB, 0, stream>>>(x, mask, cond, (float*)d_out);

    finalize_kernel<<<1, 1, 0, stream>>>((float*)d_out);
}

// Round 3
// 349.142 us; speedup vs baseline: 1.5952x; 1.5952x over previous
//
#include <hip/hip_runtime.h>
#include <hip/hip_bf16.h>

#define BB   2048
#define SS   256
#define NTOK (BB*SS)
#define FIN  3
#define CND  4
#define EMB  4
#define HID  64
#define NC   256
#define TPB  512

// LDS layout (float offsets), all 16B-aligned where float4-read:
#define OF_EW1 0        // 448
#define OF_EB1 448      // 64
#define OF_EW2 512      // 4096
#define OF_EB2 4608     // 64
#define OF_EW3 4672     // 256
#define OF_EB3 4928     // 4 (pad to 4944)
#define OF_CB  4944     // 1024
#define OF_CC  5968     // 256
#define OF_DW1 6224     // 512
#define OF_DB1 6736     // 64
#define OF_DW2 6800     // 4096
#define OF_DB2 10896    // 64
#define OF_DW3 10960    // 192
#define OF_DB3 11152    // 4
#define SMEM_F 11168    // total floats (44.7 KB)

__global__ __launch_bounds__(TPB, 4) void vqvae_main(
        const float* __restrict__ x, const float* __restrict__ mask,
        const float* __restrict__ cond,
        const float* __restrict__ ew1, const float* __restrict__ eb1,
        const float* __restrict__ ew2, const float* __restrict__ eb2,
        const float* __restrict__ ew3, const float* __restrict__ eb3,
        const float* __restrict__ cb,
        const float* __restrict__ dw1, const float* __restrict__ db1,
        const float* __restrict__ dw2, const float* __restrict__ db2,
        const float* __restrict__ dw3, const float* __restrict__ db3,
        float* __restrict__ out, float* __restrict__ loss_ws) {
    __shared__ float smem[SMEM_F];
    const int tid = threadIdx.x;

    // ---- stage all weights into LDS (in-order ds traffic only in hot loops) ----
    for (int i = tid; i < (FIN+CND)*HID; i += TPB) smem[OF_EW1+i] = ew1[i];
    for (int i = tid; i < HID;           i += TPB) smem[OF_EB1+i] = eb1[i];
    for (int i = tid; i < HID*HID;       i += TPB) smem[OF_EW2+i] = ew2[i];
    for (int i = tid; i < HID;           i += TPB) smem[OF_EB2+i] = eb2[i];
    for (int i = tid; i < HID*EMB;       i += TPB) smem[OF_EW3+i] = ew3[i];
    for (int i = tid; i < EMB;           i += TPB) smem[OF_EB3+i] = eb3[i];
    for (int i = tid; i < NC*EMB;        i += TPB) smem[OF_CB +i] = cb[i];
    for (int i = tid; i < (EMB+CND)*HID; i += TPB) smem[OF_DW1+i] = dw1[i];
    for (int i = tid; i < HID;           i += TPB) smem[OF_DB1+i] = db1[i];
    for (int i = tid; i < HID*HID;       i += TPB) smem[OF_DW2+i] = dw2[i];
    for (int i = tid; i < HID;           i += TPB) smem[OF_DB2+i] = db2[i];
    for (int i = tid; i < HID*FIN;       i += TPB) smem[OF_DW3+i] = dw3[i];
    for (int i = tid; i < FIN;           i += TPB) smem[OF_DB3+i] = db3[i];
    if (tid < NC) {  // cc from GLOBAL cb (no extra barrier needed)
        float c0 = cb[tid*EMB+0], c1 = cb[tid*EMB+1];
        float c2 = cb[tid*EMB+2], c3 = cb[tid*EMB+3];
        smem[OF_CC+tid] = ((c0*c0 + c1*c1) + c2*c2) + c3*c3;  // R2 order
    }
    __syncthreads();

    const int n  = blockIdx.x * TPB + tid;
    const int bu = n >> 8;                 // batch index (SS=256)
    const float m = mask[n];

    float cnd[CND];
    #pragma unroll
    for (int i = 0; i < CND; i++) cnd[i] = cond[bu*CND + i];

    float xin[FIN + CND];
    #pragma unroll
    for (int i = 0; i < FIN; i++) xin[i] = x[n*FIN + i] * m;
    #pragma unroll
    for (int i = 0; i < CND; i++) xin[FIN + i] = cnd[i] * m;

    // ---- encoder L1: 7 -> 64, relu; h1 fully in VGPRs (static unroll) ----
    float h1[HID];
    #pragma unroll
    for (int j = 0; j < HID; j++) {
        float a = xin[0] * smem[OF_EW1 + j];
        #pragma unroll
        for (int i = 1; i < FIN+CND; i++) a = fmaf(xin[i], smem[OF_EW1 + i*HID + j], a);
        a += smem[OF_EB1 + j];
        h1[j] = fmaxf(a, 0.0f);
    }

    // ---- encoder L2 (64->64, relu) fused with L3 (64->4): h2 never stored ----
    float z0 = 0.f, z1 = 0.f, z2 = 0.f, z3 = 0.f;
    for (int jt = 0; jt < 16; jt++) {      // dynamic: keeps code size in I$
        float a0 = 0.f, a1 = 0.f, a2 = 0.f, a3 = 0.f;
        #pragma unroll
        for (int k = 0; k < HID; k++) {    // full unroll: h1[k] stays in regs
            float4 w = *(const float4*)&smem[OF_EW2 + k*HID + jt*4];
            a0 = fmaf(h1[k], w.x, a0);
            a1 = fmaf(h1[k], w.y, a1);
            a2 = fmaf(h1[k], w.z, a2);
            a3 = fmaf(h1[k], w.w, a3);
        }
        float4 b = *(const float4*)&smem[OF_EB2 + jt*4];
        float t0 = fmaxf(a0 + b.x, 0.0f);
        float t1 = fmaxf(a1 + b.y, 0.0f);
        float t2 = fmaxf(a2 + b.z, 0.0f);
        float t3 = fmaxf(a3 + b.w, 0.0f);
        // fold into z; k-order = jt*4+{0,1,2,3} ascending == R2's sequence
        float4 w0 = *(const float4*)&smem[OF_EW3 + (jt*4+0)*EMB];
        z0 = fmaf(t0, w0.x, z0); z1 = fmaf(t0, w0.y, z1);
        z2 = fmaf(t0, w0.z, z2); z3 = fmaf(t0, w0.w, z3);
        float4 w1 = *(const float4*)&smem[OF_EW3 + (jt*4+1)*EMB];
        z0 = fmaf(t1, w1.x, z0); z1 = fmaf(t1, w1.y, z1);
        z2 = fmaf(t1, w1.z, z2); z3 = fmaf(t1, w1.w, z3);
        float4 w2 = *(const float4*)&smem[OF_EW3 + (jt*4+2)*EMB];
        z0 = fmaf(t2, w2.x, z0); z1 = fmaf(t2, w2.y, z1);
        z2 = fmaf(t2, w2.z, z2); z3 = fmaf(t2, w2.w, z3);
        float4 w3 = *(const float4*)&smem[OF_EW3 + (jt*4+3)*EMB];
        z0 = fmaf(t3, w3.x, z0); z1 = fmaf(t3, w3.y, z1);
        z2 = fmaf(t3, w3.z, z2); z3 = fmaf(t3, w3.w, z3);
    }
    z0 += smem[OF_EB3+0]; z1 += smem[OF_EB3+1];
    z2 += smem[OF_EB3+2]; z3 += smem[OF_EB3+3];

    // ---- VQ argmin: d = (zz - 2*dot) + cc, strict < (np first-min) ----
    const float zz = ((z0*z0 + z1*z1) + z2*z2) + z3*z3;
    float best = 3.4e38f;
    int   bi   = 0;
    #pragma unroll 4
    for (int ci = 0; ci < NC; ci++) {
        float4 c = *(const float4*)&smem[OF_CB + ci*EMB];
        float dot = z0 * c.x;
        dot = fmaf(z1, c.y, dot);
        dot = fmaf(z2, c.z, dot);
        dot = fmaf(z3, c.w, dot);
        float d = (zz - 2.0f*dot) + smem[OF_CC + ci];
        if (d < best) { best = d; bi = ci; }
    }
    float4 q = *(const float4*)&smem[OF_CB + bi*EMB];  // per-lane gather

    // ---- vq loss partial (scale 1.25/(N*EMB) at finalize) ----
    float e0 = z0-q.x, e1 = z1-q.y, e2 = z2-q.z, e3 = z3-q.w;
    float sq = ((e0*e0 + e1*e1) + e2*e2) + e3*e3;
    #pragma unroll
    for (int off = 32; off > 0; off >>= 1) sq += __shfl_down(sq, off, 64);
    if ((tid & 63) == 0) atomicAdd(loss_ws, sq);

    // ---- decoder L1: 8 -> 64, relu ----
    float zd[EMB + CND];
    zd[0] = q.x*m; zd[1] = q.y*m; zd[2] = q.z*m; zd[3] = q.w*m;
    #pragma unroll
    for (int i = 0; i < CND; i++) zd[EMB + i] = cnd[i] * m;

    float hd[HID];
    #pragma unroll
    for (int j = 0; j < HID; j++) {
        float a = zd[0] * smem[OF_DW1 + j];
        #pragma unroll
        for (int i = 1; i < EMB+CND; i++) a = fmaf(zd[i], smem[OF_DW1 + i*HID + j], a);
        a += smem[OF_DB1 + j];
        hd[j] = fmaxf(a, 0.0f);
    }

    // ---- decoder L2 (64->64, relu) fused with L3 (64->3) ----
    float r0 = 0.f, r1 = 0.f, r2 = 0.f;
    for (int jt = 0; jt < 16; jt++) {
        float a0 = 0.f, a1 = 0.f, a2 = 0.f, a3 = 0.f;
        #pragma unroll
        for (int k = 0; k < HID; k++) {
            float4 w = *(const float4*)&smem[OF_DW2 + k*HID + jt*4];
            a0 = fmaf(hd[k], w.x, a0);
            a1 = fmaf(hd[k], w.y, a1);
            a2 = fmaf(hd[k], w.z, a2);
            a3 = fmaf(hd[k], w.w, a3);
        }
        float4 b = *(const float4*)&smem[OF_DB2 + jt*4];
        float t0 = fmaxf(a0 + b.x, 0.0f);
        float t1 = fmaxf(a1 + b.y, 0.0f);
        float t2 = fmaxf(a2 + b.z, 0.0f);
        float t3 = fmaxf(a3 + b.w, 0.0f);
        #pragma unroll
        for (int jj = 0; jj < 4; jj++) {
            float t = (jj==0)?t0:(jj==1)?t1:(jj==2)?t2:t3;
            int j = jt*4 + jj;
            r0 = fmaf(t, smem[OF_DW3 + j*FIN + 0], r0);
            r1 = fmaf(t, smem[OF_DW3 + j*FIN + 1], r1);
            r2 = fmaf(t, smem[OF_DW3 + j*FIN + 2], r2);
        }
    }
    r0 += smem[OF_DB3+0]; r1 += smem[OF_DB3+1]; r2 += smem[OF_DB3+2];

    // ---- outputs: [x_reco | vq_loss | idx(as f32)] ----
    out[n*FIN + 0] = r0;
    out[n*FIN + 1] = r1;
    out[n*FIN + 2] = r2;
    out[NTOK*FIN + 1 + n] = (float)bi;
}

__global__ void finalize_kernel(float* out, const float* loss_ws) {
    out[NTOK*FIN] = 1.25f * loss_ws[0] * (1.0f / (float)(NTOK*EMB));
}

extern "C" void kernel_launch(void* const* d_in, const int* in_sizes, int n_in,
                              void* d_out, int out_size, void* d_ws, size_t ws_size,
                              hipStream_t stream) {
    (void)in_sizes; (void)n_in; (void)ws_size; (void)out_size;
    float* ws = (float*)d_ws;
    hipMemsetAsync(ws, 0, sizeof(float), stream);   // ws re-poisoned each call

    vqvae_main<<<NTOK/TPB, TPB, 0, stream>>>(
        (const float*)d_in[0], (const float*)d_in[1], (const float*)d_in[2],
        (const float*)d_in[3], (const float*)d_in[4], (const float*)d_in[5],
        (const float*)d_in[6], (const float*)d_in[7], (const float*)d_in[8],
        (const float*)d_in[9], (const float*)d_in[10], (const float*)d_in[11],
        (const float*)d_in[12], (const float*)d_in[13], (const float*)d_in[14],
        (const float*)d_in[15],
        (float*)d_out, ws);

    finalize_kernel<<<1, 1, 0, stream>>>((float*)d_out, ws);
}